// Round 14
// baseline (6626.231 us; speedup 1.0000x reference)
//
#include <hip/hip_runtime.h>
#include <hip/hip_fp16.h>

typedef unsigned short u16;
typedef unsigned int u32;
typedef unsigned long long u64;
typedef short s16x8 __attribute__((ext_vector_type(8)));
typedef float f32x4 __attribute__((ext_vector_type(4)));

#define BB   32
#define SS   1024
#define DD   512
#define G4   2048
#define MAXW 256
#define NWG  64                 // single merged domain: 64 WGs
#define HS   (BB*DD)            // u16 elements per h slab (32KB)

__device__ __forceinline__ u16 f2bf(float f){
  unsigned int u = __float_as_uint(f);
  u += 0x7fff + ((u >> 16) & 1);           // RNE
  return (u16)(u >> 16);
}
__device__ __forceinline__ float bf2f(u16 h){
  return __uint_as_float(((unsigned int)h) << 16);
}
__device__ __forceinline__ float sigm(float x){ return 1.f/(1.f + __expf(-x)); }
__device__ __forceinline__ float ftanh(float x){
  float ax = fabsf(x);
  float e = __expf(-2.f*ax);               // in (0,1], never overflows
  float t = (1.f - e)/(1.f + e);
  return copysignf(t, x);
}

// ---------------- prep: fp32 weights -> bf16; fused permuted bias ----------
// bias_perm[l][n] = b_ih[l][g]+b_hh[l][g], g = (n&3)*512 + (n>>2) (gate-minor)
__global__ void k_prep(const float* __restrict__ Wih, const float* __restrict__ Whh,
                       const float* __restrict__ bih, const float* __restrict__ bhh,
                       u16* __restrict__ Wih_b, u16* __restrict__ Whh_b,
                       float* __restrict__ biasp){
  long i = (long)blockIdx.x*blockDim.x + threadIdx.x;
  long n = 2l*G4*DD;
  long stride = (long)gridDim.x*blockDim.x;
  for (long k = i; k < n; k += stride){
    Wih_b[k] = f2bf(Wih[k]);
    Whh_b[k] = f2bf(Whh[k]);
  }
  for (long k = i; k < 2*G4; k += stride){
    int lyr = (int)(k / G4), nn = (int)(k % G4);
    int col = nn >> 2, q = nn & 3;
    int g = q*DD + col;
    biasp[k] = bih[lyr*G4 + g] + bhh[lyr*G4 + g];
  }
}

// ---------------- embedding gather -> bf16 [B*S][D] ------------------------
__global__ void k_embed(const int* __restrict__ x, const float* __restrict__ emb,
                        u16* __restrict__ out){
  int bs = blockIdx.x;
  int tok = x[bs];
  const float* src = emb + (size_t)tok * DD;
  u16* dst = out + (size_t)bs * DD;
  for (int d = threadIdx.x; d < DD; d += blockDim.x) dst[d] = f2bf(src[d]);
}

// ---- wait until all lanes see *p >= need (wave-uniform single-word poll) --
// budget is TOTAL across the kernel: a broken protocol fails loudly (~1s)
// with wrong output instead of hanging the harness.
__device__ __forceinline__ void waitc(const u32* p, u32 need, int& budget){
  if (need == 0u) return;
  while (budget > 0){
    u32 v = __hip_atomic_load(p, __ATOMIC_RELAXED, __HIP_MEMORY_SCOPE_AGENT);
    if (__all((int)(v >= need))) break;
    budget--;
    __builtin_amdgcn_s_sleep(1);
  }
}

// write a 16x8B-per-thread register slab into XOR-swizzled LDS
__device__ __forceinline__ void lds_write16(char* lds, int tid, const u64* d){
  #pragma unroll
  for (int j = 0; j < 16; j++){
    int e = j*256 + tid;
    int b = e >> 7, c8 = e & 127;
    *(u64*)(lds + b*1024 + ((c8*8) ^ ((b & 7) << 4))) = d[j];
  }
}

// fragment byte offset in a staged slab for (lane, kk)
#define FRAG_BYT(kk) ((lane & 15)*1024 + (((kk)*64 + (lane>>4)*16) ^ (((lane & 15) & 7) << 4)))

// ---------------- merged single-domain 2-layer persistent LSTM -------------
// 64 WGs x 256 thr, ONE sync domain. In each WG: waves 0-1 = layer 1 (8 cols,
// step k), waves 2-3 = layer 2 (8 cols, step k-1). All inputs of iteration k
// (x[k], h1[k-1], h2[k-2]) were published at iteration k-1 => one counter,
// one wait, one publish per iteration (vs two chained domains in R13).
// h1[k-1] is staged ONCE (sH1) and shared: L1 recurrent operand AND L2
// projection operand. R13 overlap idiom kept: d1/d2 issued right after
// detect; x-term covers d1's flight; h1-term MFMAs cover d2's flight.
// Buffers: h1/h2 2-slot rings (lockstep makes RING unnecessary; overwrite
// of slot s at iter k is safe because all reads of it happened at iter k-1,
// confirmed by the counter). Weights register-pinned (R8-proven).
__global__ __launch_bounds__(256, 1) void k_recur2(
    const u16* __restrict__ h_io,
    const u16* __restrict__ Wih_b,
    const u16* __restrict__ Whh_b,
    const float* __restrict__ biasp,
    u16* __restrict__ h1r,
    u16* __restrict__ h2r,
    u32* __restrict__ flags,
    u16* __restrict__ h_seq2){
  __shared__ char sX [32768];              // x[k] tile
  __shared__ char sH1[32768];              // h1[k-1] tile (shared L1+L2)
  __shared__ char sH2[32768];              // h2[k-2] tile
  const int tid = threadIdx.x;
  const int lane = tid & 63, wv = tid >> 6;
  const int wg = blockIdx.x;               // 0..63
  const bool isL2w = (wv >= 2);            // wave-level role
  const int wvl = wv & 1;                  // wave index within role

  u32* cc = flags;                         // single iteration counter

  // weights: perm gate-row pa = wg*32 + wvl*16 + (lane&15); layer by role
  const int pa = wg*32 + wvl*16 + (lane & 15);
  const size_t arow = (size_t)((pa & 3)*DD + (pa >> 2))*DD;
  const int koff = (lane >> 4)*8;
  const size_t lyrOff = isL2w ? (size_t)G4*DD : 0;
  s16x8 ahh[16], aih[16];
  #pragma unroll
  for (int kk = 0; kk < 16; kk++){
    ahh[kk] = *(const s16x8*)(Whh_b + lyrOff + arow + kk*32 + koff);
    aih[kk] = *(const s16x8*)(Wih_b + lyrOff + arow + kk*32 + koff);
  }
  #pragma unroll
  for (int kk = 0; kk < 16; kk++){         // pin in VGPRs (defeat load-sinking)
    asm volatile("" : "+v"(ahh[kk]));
    asm volatile("" : "+v"(aih[kk]));
  }

  const int oc = wg*8 + wvl*4 + (lane >> 4);      // col within the layer
  const int cl = wvl*4 + (lane >> 4);             // WG-local col (0..7)
  const int b0 = lane & 15, b1 = b0 + 16;         // lane's two batches
  const f32x4 b4 = *(const f32x4*)(biasp + (isL2w ? G4 : 0) + oc*4);
  float c0 = 0.f, cst1 = 0.f;
  int budget = 1 << 22;                    // total spin budget (anti-hang)

  u64 xd[16];
  #pragma unroll
  for (int j = 0; j < 16; j++){            // prefetch x[0]
    int e = j*256 + tid;
    xd[j] = *((const u64*)h_io + ((size_t)(e >> 7)*SS + 0)*128 + (e & 127));
  }

  for (int k = 0; k <= SS; k++){
    // ---- wait all WGs finished iteration k-1 (single coalesced poll) ----
    waitc(cc, (k > 0) ? (u32)(NWG*k) : 0u, budget);
    // ---- issue staged loads immediately (their RT hides under MFMA) ----
    u64 d1[16], d2[16];
    if (k >= 1){
      const u64* s1 = (const u64*)(h1r + (size_t)((k-1) & 1)*HS);
      #pragma unroll
      for (int j = 0; j < 16; j++)
        d1[j] = __hip_atomic_load(s1 + j*256 + tid,
                                  __ATOMIC_RELAXED, __HIP_MEMORY_SCOPE_AGENT);
    }
    if (k >= 2){
      const u64* s2 = (const u64*)(h2r + (size_t)((k-2) & 1)*HS);
      #pragma unroll
      for (int j = 0; j < 16; j++)
        d2[j] = __hip_atomic_load(s2 + j*256 + tid,
                                  __ATOMIC_RELAXED, __HIP_MEMORY_SCOPE_AGENT);
    }
    // ---- x tile -> LDS; x-term (L1 waves) covers d1's flight ----
    if (k < SS) lds_write16(sX, tid, xd);
    __syncthreads();                       // A: sX ready
    f32x4 e0 = {0.f,0.f,0.f,0.f}, e1 = {0.f,0.f,0.f,0.f};
    if (!isL2w && k < SS){
      #pragma unroll
      for (int kk = 0; kk < 16; kk++){
        int byt = FRAG_BYT(kk);
        s16x8 f0 = *(const s16x8*)(sX + byt);
        s16x8 f1 = *(const s16x8*)(sX + byt + 16*1024);
        e0 = __builtin_amdgcn_mfma_f32_16x16x32_bf16(aih[kk], f0, e0, 0, 0, 0);
        e1 = __builtin_amdgcn_mfma_f32_16x16x32_bf16(aih[kk], f1, e1, 0, 0, 0);
      }
    }
    // ---- h1[k-1] tile (SHARED): L1 recurrent + L2 projection ----
    if (k >= 1){
      lds_write16(sH1, tid, d1);           // compiler waits d1 here
      __syncthreads();                     // B: sH1 ready
      if (!isL2w){
        if (k < SS){
          #pragma unroll
          for (int kk = 0; kk < 16; kk++){
            int byt = FRAG_BYT(kk);
            s16x8 f0 = *(const s16x8*)(sH1 + byt);
            s16x8 f1 = *(const s16x8*)(sH1 + byt + 16*1024);
            e0 = __builtin_amdgcn_mfma_f32_16x16x32_bf16(ahh[kk], f0, e0, 0, 0, 0);
            e1 = __builtin_amdgcn_mfma_f32_16x16x32_bf16(ahh[kk], f1, e1, 0, 0, 0);
          }
        }
      } else {
        #pragma unroll
        for (int kk = 0; kk < 16; kk++){   // L2 projection term (covers d2)
          int byt = FRAG_BYT(kk);
          s16x8 f0 = *(const s16x8*)(sH1 + byt);
          s16x8 f1 = *(const s16x8*)(sH1 + byt + 16*1024);
          e0 = __builtin_amdgcn_mfma_f32_16x16x32_bf16(aih[kk], f0, e0, 0, 0, 0);
          e1 = __builtin_amdgcn_mfma_f32_16x16x32_bf16(aih[kk], f1, e1, 0, 0, 0);
        }
      }
    }
    // ---- h2[k-2] tile: L2 recurrent term ----
    if (k >= 2){
      lds_write16(sH2, tid, d2);           // compiler waits d2 here
      __syncthreads();                     // C: sH2 ready
      if (isL2w){
        #pragma unroll
        for (int kk = 0; kk < 16; kk++){
          int byt = FRAG_BYT(kk);
          s16x8 f0 = *(const s16x8*)(sH2 + byt);
          s16x8 f1 = *(const s16x8*)(sH2 + byt + 16*1024);
          e0 = __builtin_amdgcn_mfma_f32_16x16x32_bf16(ahh[kk], f0, e0, 0, 0, 0);
          e1 = __builtin_amdgcn_mfma_f32_16x16x32_bf16(ahh[kk], f1, e1, 0, 0, 0);
        }
      }
    }
    // ---- gates + protocol stores ----
    const bool act = (!isL2w) ? (k < SS) : (k >= 1);
    u32 p0 = 0, p1 = 0;
    if (act){
      float ig = sigm (e0[0] + b4[0]), fg = sigm (e0[1] + b4[1]);
      float gg = ftanh(e0[2] + b4[2]), og = sigm (e0[3] + b4[3]);
      c0 = fg*c0 + ig*gg;
      float hv0 = og * ftanh(c0);
      ig = sigm (e1[0] + b4[0]); fg = sigm (e1[1] + b4[1]);
      gg = ftanh(e1[2] + b4[2]); og = sigm (e1[3] + b4[3]);
      cst1 = fg*cst1 + ig*gg;
      float hv1 = og * ftanh(cst1);
      u16 hh0 = f2bf(hv0), hh1 = f2bf(hv1);
      p0 = (u32)hh0 | (((u32)__shfl((int)hh0, (lane + 16) & 63) & 0xffffu) << 16);
      p1 = (u32)hh1 | (((u32)__shfl((int)hh1, (lane + 16) & 63) & 0xffffu) << 16);
      u16* dst = (!isL2w) ? (h1r + (size_t)(k & 1)*HS)
                          : (h2r + (size_t)((k-1) & 1)*HS);
      if (((lane >> 4) & 1) == 0){
        __hip_atomic_store((u32*)(dst + (size_t)b0*DD + oc), p0,
                           __ATOMIC_RELAXED, __HIP_MEMORY_SCOPE_AGENT);
        __hip_atomic_store((u32*)(dst + (size_t)b1*DD + oc), p1,
                           __ATOMIC_RELAXED, __HIP_MEMORY_SCOPE_AGENT);
      }
    }
    asm volatile("s_waitcnt vmcnt(0)" ::: "memory");   // stores at coherence pt
    __syncthreads();                       // D: whole WG drained
    if (tid == 0) atomicAdd(cc, 1u);       // publish iteration k
    // ---- deferred non-protocol work: h_seq2 + x[k+1] prefetch ----
    if (isL2w && k >= 1 && ((lane >> 4) & 1) == 0){
      // tile-major: [t][wg(64)][b(32)][8c] -> 512B contiguous per WG
      u32* hs = (u32*)h_seq2 + (size_t)(k-1)*(HS/2) + wg*128;
      hs[b0*4 + (cl >> 1)] = p0;
      hs[b1*4 + (cl >> 1)] = p1;
    }
    if (k + 1 < SS){
      #pragma unroll
      for (int j = 0; j < 16; j++){
        int e = j*256 + tid;
        xd[j] = *((const u64*)h_io + ((size_t)(e >> 7)*SS + (k+1))*128 + (e & 127));
      }
    }
  }
}

// ---------------- ragged mean-pool + span head (TILED h_seq2) -------------
// h_seq2 layout: per step t a 32KB slab [wg(64)][b(32)][8c].
__global__ __launch_bounds__(64) void k_pool(const u16* __restrict__ h_seq,
                                             const int* __restrict__ twid,
                                             const float* __restrict__ Wout,
                                             const float* __restrict__ bout,
                                             float* __restrict__ out){
  int bw = blockIdx.x;
  int b = bw >> 8, w = bw & 255;
  const int* tw = twid + b*SS;
  __shared__ int s_lo, s_hi;
  if (threadIdx.x == 0){
    int l = 0, r = SS;
    while (l < r){ int m = (l + r) >> 1; if (tw[m] < w) l = m + 1; else r = m; }
    s_lo = l;
    r = SS;
    while (l < r){ int m = (l + r) >> 1; if (tw[m] < w + 1) l = m + 1; else r = m; }
    s_hi = l;
  }
  __syncthreads();
  int lo = s_lo, hi = s_hi, cnt = hi - lo;
  int lane = threadIdx.x;
  float p0 = 0.f, p1 = 0.f;
  if (cnt > 0){
    const char* hs = (const char*)h_seq;
    const size_t lo_off = (size_t)lane*512 + (size_t)b*16;  // wg=lane tile
    float sum[8] = {0.f,0.f,0.f,0.f,0.f,0.f,0.f,0.f};
    for (int t = lo; t < hi; t++){
      int4 v = *(const int4*)(hs + (size_t)t*32768 + lo_off);
      const u16* u = (const u16*)&v;
      #pragma unroll
      for (int j = 0; j < 8; j++) sum[j] += bf2f(u[j]);
    }
    float inv = 1.f/(float)cnt;
    #pragma unroll
    for (int j = 0; j < 8; j++){
      float pv = sum[j]*inv;
      int d = lane*8 + j;
      p0 += pv * Wout[d];
      p1 += pv * Wout[DD + d];
    }
  }
  #pragma unroll
  for (int off = 32; off; off >>= 1){
    p0 += __shfl_down(p0, off);
    p1 += __shfl_down(p1, off);
  }
  if (lane == 0){
    out[bw*2 + 0] = p0 + bout[0];
    out[bw*2 + 1] = p1 + bout[1];
  }
}

// ---------------- NLL loss over 8192 spans --------------------------------
__global__ __launch_bounds__(256) void k_loss(const float* __restrict__ logits,
                                              const int* __restrict__ labels,
                                              float* __restrict__ out_loss){
  __shared__ float red[256];
  float acc = 0.f;
  for (int i = threadIdx.x; i < BB*MAXW; i += 256){
    float z0 = logits[i*2], z1 = logits[i*2 + 1];
    float m = fmaxf(z0, z1);
    float lse = m + __logf(__expf(z0 - m) + __expf(z1 - m));
    float zl = labels[i] ? z1 : z0;
    acc += (lse - zl);
  }
  red[threadIdx.x] = acc;
  __syncthreads();
  for (int s2 = 128; s2; s2 >>= 1){
    if (threadIdx.x < s2) red[threadIdx.x] += red[threadIdx.x + s2];
    __syncthreads();
  }
  if (threadIdx.x == 0) out_loss[0] = red[0] / (float)(BB*MAXW);
}

extern "C" void kernel_launch(void* const* d_in, const int* in_sizes, int n_in,
                              void* d_out, int out_size, void* d_ws, size_t ws_size,
                              hipStream_t stream){
  (void)in_sizes; (void)n_in; (void)out_size; (void)ws_size;
  const int*   x      = (const int*)  d_in[0];
  const int*   labels = (const int*)  d_in[1];
  const int*   twid   = (const int*)  d_in[2];
  const float* emb    = (const float*)d_in[3];
  const float* Wih    = (const float*)d_in[4];
  const float* Whh    = (const float*)d_in[5];
  const float* bih    = (const float*)d_in[6];
  const float* bhh    = (const float*)d_in[7];
  const float* Wout   = (const float*)d_in[8];
  const float* bout   = (const float*)d_in[9];
  float* out = (float*)d_out;

  char* ws = (char*)d_ws;
  size_t off = 0;
  u16*   h_io   = (u16*)  (ws + off); off += (size_t)BB*SS*DD*2;    // 32 MB
  u16*   h_seq2 = (u16*)  (ws + off); off += (size_t)BB*SS*DD*2;    // 32 MB
  u16*   Wih_b  = (u16*)  (ws + off); off += (size_t)2*G4*DD*2;     // 4 MB
  u16*   Whh_b  = (u16*)  (ws + off); off += (size_t)2*G4*DD*2;     // 4 MB
  float* biasp  = (float*)(ws + off); off += (size_t)2*G4*4;        // 16 KB
  u16*   h1r    = (u16*)  (ws + off); off += (size_t)2*HS*2;        // 128 KB
  u16*   h2r    = (u16*)  (ws + off); off += (size_t)2*HS*2;        // 128 KB
  u32*   flags  = (u32*)  (ws + off); off += 1024;
  // total ~72.3 MB

  k_prep<<<2048, 256, 0, stream>>>(Wih, Whh, bih, bhh, Wih_b, Whh_b, biasp);
  k_embed<<<BB*SS, 256, 0, stream>>>(x, emb, h_io);

  hipMemsetAsync(flags, 0, 1024, stream);

  k_recur2<<<NWG, 256, 0, stream>>>(h_io, Wih_b, Whh_b, biasp,
                                    h1r, h2r, flags, h_seq2);

  k_pool<<<BB*MAXW, 64, 0, stream>>>(h_seq2, twid, Wout, bout, out);
  k_loss<<<1, 256, 0, stream>>>(out, labels, out + BB*MAXW*2);
}

// Round 15
// 4314.965 us; speedup vs baseline: 1.5356x; 1.5356x over previous
//
#include <hip/hip_runtime.h>
#include <hip/hip_fp16.h>

typedef unsigned short u16;
typedef unsigned int u32;
typedef unsigned long long u64;
typedef short s16x8 __attribute__((ext_vector_type(8)));
typedef float f32x4 __attribute__((ext_vector_type(4)));

#define BB   32
#define SS   1024
#define DD   512
#define G4   2048
#define MAXW 256
#define NWG  32                 // workgroups per layer
#define RING 8                  // h1 ring slots (pipeline window)
#define HS   (BB*DD)            // u16 elements per h slab (32KB)

__device__ __forceinline__ u16 f2bf(float f){
  unsigned int u = __float_as_uint(f);
  u += 0x7fff + ((u >> 16) & 1);           // RNE
  return (u16)(u >> 16);
}
__device__ __forceinline__ float bf2f(u16 h){
  return __uint_as_float(((unsigned int)h) << 16);
}
__device__ __forceinline__ float sigm(float x){ return 1.f/(1.f + __expf(-x)); }
__device__ __forceinline__ float ftanh(float x){
  float ax = fabsf(x);
  float e = __expf(-2.f*ax);               // in (0,1], never overflows
  float t = (1.f - e)/(1.f + e);
  return copysignf(t, x);
}

// ---------------- prep: fp32 weights -> bf16; fused permuted bias ----------
// bias_perm[l][n] = b_ih[l][g]+b_hh[l][g], g = (n&3)*512 + (n>>2) (gate-minor)
__global__ void k_prep(const float* __restrict__ Wih, const float* __restrict__ Whh,
                       const float* __restrict__ bih, const float* __restrict__ bhh,
                       u16* __restrict__ Wih_b, u16* __restrict__ Whh_b,
                       float* __restrict__ biasp){
  long i = (long)blockIdx.x*blockDim.x + threadIdx.x;
  long n = 2l*G4*DD;
  long stride = (long)gridDim.x*blockDim.x;
  for (long k = i; k < n; k += stride){
    Wih_b[k] = f2bf(Wih[k]);
    Whh_b[k] = f2bf(Whh[k]);
  }
  for (long k = i; k < 2*G4; k += stride){
    int lyr = (int)(k / G4), nn = (int)(k % G4);
    int col = nn >> 2, q = nn & 3;
    int g = q*DD + col;
    biasp[k] = bih[lyr*G4 + g] + bhh[lyr*G4 + g];
  }
}

// ---------------- embedding gather -> bf16 [B*S][D] ------------------------
__global__ void k_embed(const int* __restrict__ x, const float* __restrict__ emb,
                        u16* __restrict__ out){
  int bs = blockIdx.x;
  int tok = x[bs];
  const float* src = emb + (size_t)tok * DD;
  u16* dst = out + (size_t)bs * DD;
  for (int d = threadIdx.x; d < DD; d += blockDim.x) dst[d] = f2bf(src[d]);
}

// ---- wait until all lanes see *p1>=n1 and *p2>=n2 (wave-uniform loads) ----
// budget is TOTAL across the kernel: a broken protocol fails loudly (~1s)
// with wrong output instead of hanging the harness.
__device__ __forceinline__ void wait2(const u32* p1, u32 n1,
                                      const u32* p2, u32 n2, int& budget){
  if (n1 == 0u && n2 == 0u) return;
  while (budget > 0){
    u32 v1 = n1 ? __hip_atomic_load(p1, __ATOMIC_RELAXED, __HIP_MEMORY_SCOPE_AGENT)
                : 0xffffffffu;
    u32 v2 = n2 ? __hip_atomic_load(p2, __ATOMIC_RELAXED, __HIP_MEMORY_SCOPE_AGENT)
                : 0xffffffffu;
    int ok = (v1 >= n1) && (v2 >= n2);
    if (__all(ok)) break;
    budget--;
    __builtin_amdgcn_s_sleep(1);
  }
}

// ---- cached-counter wait: poll only if the last-seen value is too small; --
// returns (via ref) the freshest value so future gates can be skipped.
// Monotonic counter => one read proves the gate for many future steps.
__device__ __forceinline__ void waitc_cached(const u32* p, u32 need,
                                             u32& seen, int& budget){
  if (seen >= need) return;
  while (budget > 0){
    u32 v = __hip_atomic_load(p, __ATOMIC_RELAXED, __HIP_MEMORY_SCOPE_AGENT);
    if (__all((int)(v >= need))){ seen = v; break; }
    budget--;
    __builtin_amdgcn_s_sleep(1);
  }
}

// ---- stage a 32x512 bf16 slab (32KB) into XOR-swizzled LDS ---------------
// 256 threads x 16 x 8B agent-atomic loads (MALL-coherent, R2/R7-proven).
__device__ __forceinline__ void stage_h(const u16* slab, char* lds, int tid){
  u64 d[16];
  #pragma unroll
  for (int j = 0; j < 16; j++)
    d[j] = __hip_atomic_load((const u64*)slab + j*256 + tid,
                             __ATOMIC_RELAXED, __HIP_MEMORY_SCOPE_AGENT);
  #pragma unroll
  for (int j = 0; j < 16; j++){
    int e = j*256 + tid;
    int b = e >> 7, c8 = e & 127;
    *(u64*)(lds + b*1024 + ((c8*8) ^ ((b & 7) << 4))) = d[j];
  }
}

// write a 16x8B-per-thread register slab into XOR-swizzled LDS
__device__ __forceinline__ void lds_write16(char* lds, int tid, const u64* d){
  #pragma unroll
  for (int j = 0; j < 16; j++){
    int e = j*256 + tid;
    int b = e >> 7, c8 = e & 127;
    *(u64*)(lds + b*1024 + ((c8*8) ^ ((b & 7) << 4))) = d[j];
  }
}

// fragment byte offset in a staged slab for (lane, kk)
#define FRAG_BYT(kk) ((lane & 15)*1024 + (((kk)*64 + (lane>>4)*16) ^ (((lane & 15) & 7) << 4)))

// ---------------- fused 2-layer persistent LSTM recurrence ----------------
// R13 baseline (proven 4.31ms): 64 WGs x 256 thr; WGs 0..31 layer 1 (W_ih1@x_t
// on the fly, x-term pre-wait), 32..63 layer 2 (1 step behind, W_ih2@h1_t on
// the fly); atomicAdd counter publish; weights register-pinned; h_seq2
// deferred + tile-major; L2: d1 issued early, consumed first, h1-term MFMA
// covers d2. THIS ROUND (one axis): L2's c1 gate uses a CACHED counter read
// — L1 runs ~RING ahead, so one read of the monotonic counter (returning
// ~32(t+RING)) proves the gate for ~8 future steps; the ~0.7us MALL poll RT
// is removed from ~7/8 of L2's iterations (the pacing loop).
// h1: 8-slot ring + backpressure (c2 >= 32(t-7)); h2: 2-slot ring (safe:
// peers' reads of slot (t-1)&1 precede their step-t publish).
__global__ __launch_bounds__(256, 1) void k_recur2(
    const u16* __restrict__ h_io,
    const u16* __restrict__ Wih_b,
    const u16* __restrict__ Whh_b,
    const float* __restrict__ biasp,
    u16* __restrict__ h1r,
    u16* __restrict__ h2r,
    u32* __restrict__ flags,
    u16* __restrict__ h_seq2){
  __shared__ char hX[32768];               // L1: x tile   | L2: h1 tile
  __shared__ char hH[32768];               // L1: h1 tile  | L2: h2 tile
  const int tid = threadIdx.x;
  const int lane = tid & 63, wv = tid >> 6;
  const int wg = blockIdx.x;
  const bool isL2 = wg >= NWG;
  const int id = wg & (NWG - 1);

  u32* c1 = flags;                         // layer-1 progress (own 128B line)
  u32* c2 = flags + 64;                    // layer-2 progress

  // weight A-fragments: perm gate-row pa = id*64 + wv*16 + (lane&15)
  const int pa = id*64 + wv*16 + (lane & 15);
  const size_t arow = (size_t)((pa & 3)*DD + (pa >> 2))*DD;
  const int koff = (lane >> 4)*8;
  const size_t lyrOff = isL2 ? (size_t)G4*DD : 0;
  s16x8 ahh[16], aih[16];
  #pragma unroll
  for (int kk = 0; kk < 16; kk++){
    ahh[kk] = *(const s16x8*)(Whh_b + lyrOff + arow + kk*32 + koff);
    aih[kk] = *(const s16x8*)(Wih_b + lyrOff + arow + kk*32 + koff);
  }
  #pragma unroll
  for (int kk = 0; kk < 16; kk++){         // pin in VGPRs (defeat load-sinking)
    asm volatile("" : "+v"(ahh[kk]));
    asm volatile("" : "+v"(aih[kk]));
  }

  const int oc = id*16 + wv*4 + (lane >> 4);      // lane's h column
  const int cl = wv*4 + (lane >> 4);              // col local to WG (0..15)
  const int b0 = lane & 15, b1 = b0 + 16;         // lane's two batches
  const f32x4 b4 = *(const f32x4*)(biasp + (isL2 ? G4 : 0) + oc*4);
  float c0 = 0.f, cst1 = 0.f;
  int budget = 1 << 22;                    // total spin budget (anti-hang)

  if (!isL2){
    // ============================ layer 1 ============================
    for (int t = 0; t < SS; t++){
      // ---- independent phase: stage x_t, compute x-term (pre-wait) ----
      u64 xd[16];
      #pragma unroll
      for (int j = 0; j < 16; j++){
        int e = j*256 + tid;
        xd[j] = *((const u64*)h_io + ((size_t)(e >> 7)*SS + t)*128 + (e & 127));
      }
      lds_write16(hX, tid, xd);
      __syncthreads();                     // A: hX ready
      f32x4 e0 = {0.f,0.f,0.f,0.f}, e1 = {0.f,0.f,0.f,0.f};
      #pragma unroll
      for (int kk = 0; kk < 16; kk++){
        int byt = FRAG_BYT(kk);
        s16x8 f0 = *(const s16x8*)(hX + byt);
        s16x8 f1 = *(const s16x8*)(hX + byt + 16*1024);
        e0 = __builtin_amdgcn_mfma_f32_16x16x32_bf16(aih[kk], f0, e0, 0, 0, 0);
        e1 = __builtin_amdgcn_mfma_f32_16x16x32_bf16(aih[kk], f1, e1, 0, 0, 0);
      }
      // ---- dependent phase: wait h1[t-1] (+ ring backpressure) ----
      u32 n1 = (t > 0) ? (u32)(NWG*t) : 0u;
      u32 n2 = (t >= RING) ? (u32)(NWG*(t - RING + 1)) : 0u;
      wait2(c1, n1, c2, n2, budget);
      if (t > 0){
        stage_h(h1r + (size_t)((t-1) & (RING-1))*HS, hH, tid);
        __syncthreads();                   // B: hH ready
        #pragma unroll
        for (int kk = 0; kk < 16; kk++){
          int byt = FRAG_BYT(kk);
          s16x8 f0 = *(const s16x8*)(hH + byt);
          s16x8 f1 = *(const s16x8*)(hH + byt + 16*1024);
          e0 = __builtin_amdgcn_mfma_f32_16x16x32_bf16(ahh[kk], f0, e0, 0, 0, 0);
          e1 = __builtin_amdgcn_mfma_f32_16x16x32_bf16(ahh[kk], f1, e1, 0, 0, 0);
        }
      }
      // ---- gates + publish ----
      float ig = sigm (e0[0] + b4[0]), fg = sigm (e0[1] + b4[1]);
      float gg = ftanh(e0[2] + b4[2]), og = sigm (e0[3] + b4[3]);
      c0 = fg*c0 + ig*gg;
      float hv0 = og * ftanh(c0);
      ig = sigm (e1[0] + b4[0]); fg = sigm (e1[1] + b4[1]);
      gg = ftanh(e1[2] + b4[2]); og = sigm (e1[3] + b4[3]);
      cst1 = fg*cst1 + ig*gg;
      float hv1 = og * ftanh(cst1);
      u16 hh0 = f2bf(hv0), hh1 = f2bf(hv1);
      u32 p0 = (u32)hh0 | (((u32)__shfl((int)hh0, (lane + 16) & 63) & 0xffffu) << 16);
      u32 p1 = (u32)hh1 | (((u32)__shfl((int)hh1, (lane + 16) & 63) & 0xffffu) << 16);
      u16* dst = h1r + (size_t)(t & (RING-1))*HS;
      if (((lane >> 4) & 1) == 0){
        __hip_atomic_store((u32*)(dst + (size_t)b0*DD + oc), p0,
                           __ATOMIC_RELAXED, __HIP_MEMORY_SCOPE_AGENT);
        __hip_atomic_store((u32*)(dst + (size_t)b1*DD + oc), p1,
                           __ATOMIC_RELAXED, __HIP_MEMORY_SCOPE_AGENT);
      }
      asm volatile("s_waitcnt vmcnt(0)" ::: "memory");
      __syncthreads();                     // C: all stores drained, LDS free
      if (tid == 0) atomicAdd(c1, 1u);
    }
  } else {
    // ============================ layer 2 ============================
    u32 c1seen = 0;                        // cached last-read of c1
    for (int t = 0; t < SS; t++){
      u64 d1[16], d2[16];
      // h1[t] gate: cached — L1 runs RING ahead, one read proves ~8 steps
      waitc_cached(c1, (u32)(NWG*(t+1)), c1seen, budget);
      {
        const u64* s1 = (const u64*)(h1r + (size_t)(t & (RING-1))*HS);
        #pragma unroll
        for (int j = 0; j < 16; j++)
          d1[j] = __hip_atomic_load(s1 + j*256 + tid,
                                    __ATOMIC_RELAXED, __HIP_MEMORY_SCOPE_AGENT);
      }
      // peers' h2[t-1]: the real wait (d1 flies through it); then issue d2
      if (t > 0){
        wait2(c2, (u32)(NWG*t), c2, 0u, budget);
        const u64* s2 = (const u64*)(h2r + (size_t)((t-1) & 1)*HS);
        #pragma unroll
        for (int j = 0; j < 16; j++)
          d2[j] = __hip_atomic_load(s2 + j*256 + tid,
                                    __ATOMIC_RELAXED, __HIP_MEMORY_SCOPE_AGENT);
      }
      // consume d1 first (arrived during the c2 wait)
      f32x4 e0 = {0.f,0.f,0.f,0.f}, e1 = {0.f,0.f,0.f,0.f};
      lds_write16(hX, tid, d1);
      __syncthreads();                     // A: hX ready
      #pragma unroll
      for (int kk = 0; kk < 16; kk++){     // h1-term MFMA covers d2's flight
        int byt = FRAG_BYT(kk);
        s16x8 f0 = *(const s16x8*)(hX + byt);
        s16x8 f1 = *(const s16x8*)(hX + byt + 16*1024);
        e0 = __builtin_amdgcn_mfma_f32_16x16x32_bf16(aih[kk], f0, e0, 0, 0, 0);
        e1 = __builtin_amdgcn_mfma_f32_16x16x32_bf16(aih[kk], f1, e1, 0, 0, 0);
      }
      if (t > 0){
        lds_write16(hH, tid, d2);          // compiler waits d2 here
        __syncthreads();                   // B: hH ready
        #pragma unroll
        for (int kk = 0; kk < 16; kk++){
          int byt = FRAG_BYT(kk);
          s16x8 f0 = *(const s16x8*)(hH + byt);
          s16x8 f1 = *(const s16x8*)(hH + byt + 16*1024);
          e0 = __builtin_amdgcn_mfma_f32_16x16x32_bf16(ahh[kk], f0, e0, 0, 0, 0);
          e1 = __builtin_amdgcn_mfma_f32_16x16x32_bf16(ahh[kk], f1, e1, 0, 0, 0);
        }
      }
      // ---- gates ----
      float ig = sigm (e0[0] + b4[0]), fg = sigm (e0[1] + b4[1]);
      float gg = ftanh(e0[2] + b4[2]), og = sigm (e0[3] + b4[3]);
      c0 = fg*c0 + ig*gg;
      float hv0 = og * ftanh(c0);
      ig = sigm (e1[0] + b4[0]); fg = sigm (e1[1] + b4[1]);
      gg = ftanh(e1[2] + b4[2]); og = sigm (e1[3] + b4[3]);
      cst1 = fg*cst1 + ig*gg;
      float hv1 = og * ftanh(cst1);
      u16 hh0 = f2bf(hv0), hh1 = f2bf(hv1);
      u32 p0 = (u32)hh0 | (((u32)__shfl((int)hh0, (lane + 16) & 63) & 0xffffu) << 16);
      u32 p1 = (u32)hh1 | (((u32)__shfl((int)hh1, (lane + 16) & 63) & 0xffffu) << 16);
      // sync-critical stores only (h2r), then drain + publish
      u16* dst = h2r + (size_t)(t & 1)*HS;
      if (((lane >> 4) & 1) == 0){
        __hip_atomic_store((u32*)(dst + (size_t)b0*DD + oc), p0,
                           __ATOMIC_RELAXED, __HIP_MEMORY_SCOPE_AGENT);
        __hip_atomic_store((u32*)(dst + (size_t)b1*DD + oc), p1,
                           __ATOMIC_RELAXED, __HIP_MEMORY_SCOPE_AGENT);
      }
      asm volatile("s_waitcnt vmcnt(0)" ::: "memory");
      __syncthreads();                     // C
      if (tid == 0) atomicAdd(c2, 1u);
      // deferred, non-protocol h_seq2 stores: TILE-MAJOR, full-line bursts
      if (((lane >> 4) & 1) == 0){
        u32* hs = (u32*)h_seq2 + (size_t)t*(HS/2) + id*256;
        hs[b0*8 + (cl >> 1)] = p0;
        hs[b1*8 + (cl >> 1)] = p1;
      }
    }
  }
}

// ---------------- ragged mean-pool + span head (TILED h_seq2) -------------
// h_seq2 layout: per step t a 32KB tile-major slab [tile][b][16c]. (R9-proven)
__global__ __launch_bounds__(64) void k_pool(const u16* __restrict__ h_seq,
                                             const int* __restrict__ twid,
                                             const float* __restrict__ Wout,
                                             const float* __restrict__ bout,
                                             float* __restrict__ out){
  int bw = blockIdx.x;
  int b = bw >> 8, w = bw & 255;
  const int* tw = twid + b*SS;
  __shared__ int s_lo, s_hi;
  if (threadIdx.x == 0){
    int l = 0, r = SS;
    while (l < r){ int m = (l + r) >> 1; if (tw[m] < w) l = m + 1; else r = m; }
    s_lo = l;
    r = SS;
    while (l < r){ int m = (l + r) >> 1; if (tw[m] < w + 1) l = m + 1; else r = m; }
    s_hi = l;
  }
  __syncthreads();
  int lo = s_lo, hi = s_hi, cnt = hi - lo;
  int lane = threadIdx.x;
  float p0 = 0.f, p1 = 0.f;
  if (cnt > 0){
    const char* hs = (const char*)h_seq;
    const size_t lo_off = (size_t)(lane >> 1)*1024 + (size_t)b*32 + (lane & 1)*16;
    float sum[8] = {0.f,0.f,0.f,0.f,0.f,0.f,0.f,0.f};
    for (int t = lo; t < hi; t++){
      int4 v = *(const int4*)(hs + (size_t)t*32768 + lo_off);
      const u16* u = (const u16*)&v;
      #pragma unroll
      for (int j = 0; j < 8; j++) sum[j] += bf2f(u[j]);
    }
    float inv = 1.f/(float)cnt;
    #pragma unroll
    for (int j = 0; j < 8; j++){
      float pv = sum[j]*inv;
      int d = lane*8 + j;
      p0 += pv * Wout[d];
      p1 += pv * Wout[DD + d];
    }
  }
  #pragma unroll
  for (int off = 32; off; off >>= 1){
    p0 += __shfl_down(p0, off);
    p1 += __shfl_down(p1, off);
  }
  if (lane == 0){
    out[bw*2 + 0] = p0 + bout[0];
    out[bw*2 + 1] = p1 + bout[1];
  }
}

// ---------------- NLL loss over 8192 spans --------------------------------
__global__ __launch_bounds__(256) void k_loss(const float* __restrict__ logits,
                                              const int* __restrict__ labels,
                                              float* __restrict__ out_loss){
  __shared__ float red[256];
  float acc = 0.f;
  for (int i = threadIdx.x; i < BB*MAXW; i += 256){
    float z0 = logits[i*2], z1 = logits[i*2 + 1];
    float m = fmaxf(z0, z1);
    float lse = m + __logf(__expf(z0 - m) + __expf(z1 - m));
    float zl = labels[i] ? z1 : z0;
    acc += (lse - zl);
  }
  red[threadIdx.x] = acc;
  __syncthreads();
  for (int s2 = 128; s2; s2 >>= 1){
    if (threadIdx.x < s2) red[threadIdx.x] += red[threadIdx.x + s2];
    __syncthreads();
  }
  if (threadIdx.x == 0) out_loss[0] = red[0] / (float)(BB*MAXW);
}

extern "C" void kernel_launch(void* const* d_in, const int* in_sizes, int n_in,
                              void* d_out, int out_size, void* d_ws, size_t ws_size,
                              hipStream_t stream){
  (void)in_sizes; (void)n_in; (void)out_size; (void)ws_size;
  const int*   x      = (const int*)  d_in[0];
  const int*   labels = (const int*)  d_in[1];
  const int*   twid   = (const int*)  d_in[2];
  const float* emb    = (const float*)d_in[3];
  const float* Wih    = (const float*)d_in[4];
  const float* Whh    = (const float*)d_in[5];
  const float* bih    = (const float*)d_in[6];
  const float* bhh    = (const float*)d_in[7];
  const float* Wout   = (const float*)d_in[8];
  const float* bout   = (const float*)d_in[9];
  float* out = (float*)d_out;

  char* ws = (char*)d_ws;
  size_t off = 0;
  u16*   h_io   = (u16*)  (ws + off); off += (size_t)BB*SS*DD*2;    // 32 MB
  u16*   h_seq2 = (u16*)  (ws + off); off += (size_t)BB*SS*DD*2;    // 32 MB
  u16*   Wih_b  = (u16*)  (ws + off); off += (size_t)2*G4*DD*2;     // 4 MB
  u16*   Whh_b  = (u16*)  (ws + off); off += (size_t)2*G4*DD*2;     // 4 MB
  float* biasp  = (float*)(ws + off); off += (size_t)2*G4*4;        // 16 KB
  u16*   h1r    = (u16*)  (ws + off); off += (size_t)RING*HS*2;     // 256 KB
  u16*   h2r    = (u16*)  (ws + off); off += (size_t)2*HS*2;        // 64 KB
  u32*   flags  = (u32*)  (ws + off); off += 1024;
  // total ~72.3 MB

  k_prep<<<2048, 256, 0, stream>>>(Wih, Whh, bih, bhh, Wih_b, Whh_b, biasp);
  k_embed<<<BB*SS, 256, 0, stream>>>(x, emb, h_io);

  hipMemsetAsync(flags, 0, 1024, stream);

  k_recur2<<<2*NWG, 256, 0, stream>>>(h_io, Wih_b, Whh_b, biasp,
                                      h1r, h2r, flags, h_seq2);

  k_pool<<<BB*MAXW, 64, 0, stream>>>(h_seq2, twid, Wout, bout, out);
  k_loss<<<1, 256, 0, stream>>>(out, labels, out + BB*MAXW*2);
}

// Round 16
// 4293.553 us; speedup vs baseline: 1.5433x; 1.0050x over previous
//
#include <hip/hip_runtime.h>
#include <hip/hip_fp16.h>

typedef unsigned short u16;
typedef unsigned int u32;
typedef unsigned long long u64;
typedef short s16x8 __attribute__((ext_vector_type(8)));
typedef float f32x4 __attribute__((ext_vector_type(4)));

#define BB   32
#define SS   1024
#define DD   512
#define G4   2048
#define MAXW 256
#define NWG  32                 // workgroups per layer
#define RING 8                  // h1 ring slots (pipeline window)
#define HS   (BB*DD)            // u16 elements per h slab (32KB)

__device__ __forceinline__ u16 f2bf(float f){
  unsigned int u = __float_as_uint(f);
  u += 0x7fff + ((u >> 16) & 1);           // RNE
  return (u16)(u >> 16);
}
__device__ __forceinline__ float bf2f(u16 h){
  return __uint_as_float(((unsigned int)h) << 16);
}
__device__ __forceinline__ float sigm(float x){ return 1.f/(1.f + __expf(-x)); }
__device__ __forceinline__ float ftanh(float x){
  float ax = fabsf(x);
  float e = __expf(-2.f*ax);               // in (0,1], never overflows
  float t = (1.f - e)/(1.f + e);
  return copysignf(t, x);
}

// ---------------- prep: fp32 weights -> bf16; fused permuted bias ----------
// bias_perm[l][n] = b_ih[l][g]+b_hh[l][g], g = (n&3)*512 + (n>>2) (gate-minor)
__global__ void k_prep(const float* __restrict__ Wih, const float* __restrict__ Whh,
                       const float* __restrict__ bih, const float* __restrict__ bhh,
                       u16* __restrict__ Wih_b, u16* __restrict__ Whh_b,
                       float* __restrict__ biasp){
  long i = (long)blockIdx.x*blockDim.x + threadIdx.x;
  long n = 2l*G4*DD;
  long stride = (long)gridDim.x*blockDim.x;
  for (long k = i; k < n; k += stride){
    Wih_b[k] = f2bf(Wih[k]);
    Whh_b[k] = f2bf(Whh[k]);
  }
  for (long k = i; k < 2*G4; k += stride){
    int lyr = (int)(k / G4), nn = (int)(k % G4);
    int col = nn >> 2, q = nn & 3;
    int g = q*DD + col;
    biasp[k] = bih[lyr*G4 + g] + bhh[lyr*G4 + g];
  }
}

// ---------------- embedding gather -> bf16 [B*S][D] ------------------------
__global__ void k_embed(const int* __restrict__ x, const float* __restrict__ emb,
                        u16* __restrict__ out){
  int bs = blockIdx.x;
  int tok = x[bs];
  const float* src = emb + (size_t)tok * DD;
  u16* dst = out + (size_t)bs * DD;
  for (int d = threadIdx.x; d < DD; d += blockDim.x) dst[d] = f2bf(src[d]);
}

// ---- wait until all lanes see *p1>=n1 and *p2>=n2 (wave-uniform loads) ----
// budget is TOTAL across the kernel: a broken protocol fails loudly (~1s)
// with wrong output instead of hanging the harness.
__device__ __forceinline__ void wait2(const u32* p1, u32 n1,
                                      const u32* p2, u32 n2, int& budget){
  if (n1 == 0u && n2 == 0u) return;
  while (budget > 0){
    u32 v1 = n1 ? __hip_atomic_load(p1, __ATOMIC_RELAXED, __HIP_MEMORY_SCOPE_AGENT)
                : 0xffffffffu;
    u32 v2 = n2 ? __hip_atomic_load(p2, __ATOMIC_RELAXED, __HIP_MEMORY_SCOPE_AGENT)
                : 0xffffffffu;
    int ok = (v1 >= n1) && (v2 >= n2);
    if (__all(ok)) break;
    budget--;
    __builtin_amdgcn_s_sleep(1);
  }
}

// ---- cached-counter wait (R15): one read of the monotonic counter proves --
// the gate for many future steps.
__device__ __forceinline__ void waitc_cached(const u32* p, u32 need,
                                             u32& seen, int& budget){
  if (seen >= need) return;
  while (budget > 0){
    u32 v = __hip_atomic_load(p, __ATOMIC_RELAXED, __HIP_MEMORY_SCOPE_AGENT);
    if (__all((int)(v >= need))){ seen = v; break; }
    budget--;
    __builtin_amdgcn_s_sleep(1);
  }
}

// ---- TILE-MAJOR slab <-> swizzled LDS (R9-proven mapping) -----------------
// slab layout: [tile=WGid(32)][b(32)][16c] (1KB per tile, 32B per (tile,b)).
// Linear 8B loads are layout-agnostic; only the LDS scatter mapping encodes
// the layout. LDS result = logical [b][512c] rows, XOR-swizzled (FRAG_BYT).
__device__ __forceinline__ void lds_write16_tl(char* lds, int tid, const u64* d){
  #pragma unroll
  for (int j = 0; j < 16; j++){
    int e = j*256 + tid;
    int tile = e >> 7, u = e & 127;
    int b = u >> 2, c4 = u & 3;
    *(u64*)(lds + b*1024 + ((tile*32 + c4*8) ^ ((b & 7) << 4))) = d[j];
  }
}
__device__ __forceinline__ void stage_tl(const u16* slab, char* lds, int tid){
  u64 d[16];
  #pragma unroll
  for (int j = 0; j < 16; j++)
    d[j] = __hip_atomic_load((const u64*)slab + j*256 + tid,
                             __ATOMIC_RELAXED, __HIP_MEMORY_SCOPE_AGENT);
  lds_write16_tl(lds, tid, d);
}

// write a 16x8B-per-thread ROW-MAJOR register slab into XOR-swizzled LDS
// (used for the x tile, whose global layout is row-major [b*S+t][512])
__device__ __forceinline__ void lds_write16(char* lds, int tid, const u64* d){
  #pragma unroll
  for (int j = 0; j < 16; j++){
    int e = j*256 + tid;
    int b = e >> 7, c8 = e & 127;
    *(u64*)(lds + b*1024 + ((c8*8) ^ ((b & 7) << 4))) = d[j];
  }
}

// fragment byte offset in a staged slab for (lane, kk)
#define FRAG_BYT(kk) ((lane & 15)*1024 + (((kk)*64 + (lane>>4)*16) ^ (((lane & 15) & 7) << 4)))

// ---------------- fused 2-layer persistent LSTM recurrence ----------------
// R13/R15 baseline (proven 4.31ms): 64 WGs x 256 thr; WGs 0..31 layer 1
// (W_ih1@x_t on the fly, x-term pre-wait), 32..63 layer 2 (1 step behind,
// W_ih2@h1_t on the fly); atomicAdd counter publish; weights register-pinned;
// h_seq2 deferred tile-major; L2 d1-early/d1-first overlap; cached c1 gate.
// THIS ROUND (one axis): PROTOCOL slabs h1r/h2r become TILE-MAJOR
// [tile=WGid][b][16c] -> each WG's step output is ONE contiguous 1KB burst
// (8 full 128B lines) instead of 256 scattered 4B stores over 32 partial
// lines. The pre-publish vmcnt(0) drain (critical path in BOTH layers'
// lockstep chains) collects 4x fewer line acks. Readers use the R9-proven
// stage_tiled mapping; writer/reader mappings verified inverse.
__global__ __launch_bounds__(256, 1) void k_recur2(
    const u16* __restrict__ h_io,
    const u16* __restrict__ Wih_b,
    const u16* __restrict__ Whh_b,
    const float* __restrict__ biasp,
    u16* __restrict__ h1r,
    u16* __restrict__ h2r,
    u32* __restrict__ flags,
    u16* __restrict__ h_seq2){
  __shared__ char hX[32768];               // L1: x tile   | L2: h1 tile
  __shared__ char hH[32768];               // L1: h1 tile  | L2: h2 tile
  const int tid = threadIdx.x;
  const int lane = tid & 63, wv = tid >> 6;
  const int wg = blockIdx.x;
  const bool isL2 = wg >= NWG;
  const int id = wg & (NWG - 1);

  u32* c1 = flags;                         // layer-1 progress (own 128B line)
  u32* c2 = flags + 64;                    // layer-2 progress

  // weight A-fragments: perm gate-row pa = id*64 + wv*16 + (lane&15)
  const int pa = id*64 + wv*16 + (lane & 15);
  const size_t arow = (size_t)((pa & 3)*DD + (pa >> 2))*DD;
  const int koff = (lane >> 4)*8;
  const size_t lyrOff = isL2 ? (size_t)G4*DD : 0;
  s16x8 ahh[16], aih[16];
  #pragma unroll
  for (int kk = 0; kk < 16; kk++){
    ahh[kk] = *(const s16x8*)(Whh_b + lyrOff + arow + kk*32 + koff);
    aih[kk] = *(const s16x8*)(Wih_b + lyrOff + arow + kk*32 + koff);
  }
  #pragma unroll
  for (int kk = 0; kk < 16; kk++){         // pin in VGPRs (defeat load-sinking)
    asm volatile("" : "+v"(ahh[kk]));
    asm volatile("" : "+v"(aih[kk]));
  }

  const int oc = id*16 + wv*4 + (lane >> 4);      // lane's h column
  const int cl = wv*4 + (lane >> 4);              // col local to WG (0..15)
  const int b0 = lane & 15, b1 = b0 + 16;         // lane's two batches
  const f32x4 b4 = *(const f32x4*)(biasp + (isL2 ? G4 : 0) + oc*4);
  float c0 = 0.f, cst1 = 0.f;
  int budget = 1 << 22;                    // total spin budget (anti-hang)

  if (!isL2){
    // ============================ layer 1 ============================
    for (int t = 0; t < SS; t++){
      // ---- independent phase: stage x_t, compute x-term (pre-wait) ----
      u64 xd[16];
      #pragma unroll
      for (int j = 0; j < 16; j++){
        int e = j*256 + tid;
        xd[j] = *((const u64*)h_io + ((size_t)(e >> 7)*SS + t)*128 + (e & 127));
      }
      lds_write16(hX, tid, xd);
      __syncthreads();                     // A: hX ready
      f32x4 e0 = {0.f,0.f,0.f,0.f}, e1 = {0.f,0.f,0.f,0.f};
      #pragma unroll
      for (int kk = 0; kk < 16; kk++){
        int byt = FRAG_BYT(kk);
        s16x8 f0 = *(const s16x8*)(hX + byt);
        s16x8 f1 = *(const s16x8*)(hX + byt + 16*1024);
        e0 = __builtin_amdgcn_mfma_f32_16x16x32_bf16(aih[kk], f0, e0, 0, 0, 0);
        e1 = __builtin_amdgcn_mfma_f32_16x16x32_bf16(aih[kk], f1, e1, 0, 0, 0);
      }
      // ---- dependent phase: wait h1[t-1] (+ ring backpressure) ----
      u32 n1 = (t > 0) ? (u32)(NWG*t) : 0u;
      u32 n2 = (t >= RING) ? (u32)(NWG*(t - RING + 1)) : 0u;
      wait2(c1, n1, c2, n2, budget);
      if (t > 0){
        stage_tl(h1r + (size_t)((t-1) & (RING-1))*HS, hH, tid);
        __syncthreads();                   // B: hH ready
        #pragma unroll
        for (int kk = 0; kk < 16; kk++){
          int byt = FRAG_BYT(kk);
          s16x8 f0 = *(const s16x8*)(hH + byt);
          s16x8 f1 = *(const s16x8*)(hH + byt + 16*1024);
          e0 = __builtin_amdgcn_mfma_f32_16x16x32_bf16(ahh[kk], f0, e0, 0, 0, 0);
          e1 = __builtin_amdgcn_mfma_f32_16x16x32_bf16(ahh[kk], f1, e1, 0, 0, 0);
        }
      }
      // ---- gates + publish ----
      float ig = sigm (e0[0] + b4[0]), fg = sigm (e0[1] + b4[1]);
      float gg = ftanh(e0[2] + b4[2]), og = sigm (e0[3] + b4[3]);
      c0 = fg*c0 + ig*gg;
      float hv0 = og * ftanh(c0);
      ig = sigm (e1[0] + b4[0]); fg = sigm (e1[1] + b4[1]);
      gg = ftanh(e1[2] + b4[2]); og = sigm (e1[3] + b4[3]);
      cst1 = fg*cst1 + ig*gg;
      float hv1 = og * ftanh(cst1);
      u16 hh0 = f2bf(hv0), hh1 = f2bf(hv1);
      u32 p0 = (u32)hh0 | (((u32)__shfl((int)hh0, (lane + 16) & 63) & 0xffffu) << 16);
      u32 p1 = (u32)hh1 | (((u32)__shfl((int)hh1, (lane + 16) & 63) & 0xffffu) << 16);
      // TILE-MAJOR protocol store: WG's 1KB contiguous burst (8 full lines)
      u32* d32 = (u32*)(h1r + (size_t)(t & (RING-1))*HS) + id*256;
      if (((lane >> 4) & 1) == 0){
        __hip_atomic_store(&d32[b0*8 + (cl >> 1)], p0,
                           __ATOMIC_RELAXED, __HIP_MEMORY_SCOPE_AGENT);
        __hip_atomic_store(&d32[b1*8 + (cl >> 1)], p1,
                           __ATOMIC_RELAXED, __HIP_MEMORY_SCOPE_AGENT);
      }
      asm volatile("s_waitcnt vmcnt(0)" ::: "memory");
      __syncthreads();                     // C: all stores drained, LDS free
      if (tid == 0) atomicAdd(c1, 1u);
    }
  } else {
    // ============================ layer 2 ============================
    u32 c1seen = 0;                        // cached last-read of c1
    for (int t = 0; t < SS; t++){
      u64 d1[16], d2[16];
      // h1[t] gate: cached — L1 runs RING ahead, one read proves ~8 steps
      waitc_cached(c1, (u32)(NWG*(t+1)), c1seen, budget);
      {
        const u64* s1 = (const u64*)(h1r + (size_t)(t & (RING-1))*HS);
        #pragma unroll
        for (int j = 0; j < 16; j++)
          d1[j] = __hip_atomic_load(s1 + j*256 + tid,
                                    __ATOMIC_RELAXED, __HIP_MEMORY_SCOPE_AGENT);
      }
      // peers' h2[t-1]: the real wait (d1 flies through it); then issue d2
      if (t > 0){
        wait2(c2, (u32)(NWG*t), c2, 0u, budget);
        const u64* s2 = (const u64*)(h2r + (size_t)((t-1) & 1)*HS);
        #pragma unroll
        for (int j = 0; j < 16; j++)
          d2[j] = __hip_atomic_load(s2 + j*256 + tid,
                                    __ATOMIC_RELAXED, __HIP_MEMORY_SCOPE_AGENT);
      }
      // consume d1 first (arrived during the c2 wait)
      f32x4 e0 = {0.f,0.f,0.f,0.f}, e1 = {0.f,0.f,0.f,0.f};
      lds_write16_tl(hX, tid, d1);
      __syncthreads();                     // A: hX ready
      #pragma unroll
      for (int kk = 0; kk < 16; kk++){     // h1-term MFMA covers d2's flight
        int byt = FRAG_BYT(kk);
        s16x8 f0 = *(const s16x8*)(hX + byt);
        s16x8 f1 = *(const s16x8*)(hX + byt + 16*1024);
        e0 = __builtin_amdgcn_mfma_f32_16x16x32_bf16(aih[kk], f0, e0, 0, 0, 0);
        e1 = __builtin_amdgcn_mfma_f32_16x16x32_bf16(aih[kk], f1, e1, 0, 0, 0);
      }
      if (t > 0){
        lds_write16_tl(hH, tid, d2);       // compiler waits d2 here
        __syncthreads();                   // B: hH ready
        #pragma unroll
        for (int kk = 0; kk < 16; kk++){
          int byt = FRAG_BYT(kk);
          s16x8 f0 = *(const s16x8*)(hH + byt);
          s16x8 f1 = *(const s16x8*)(hH + byt + 16*1024);
          e0 = __builtin_amdgcn_mfma_f32_16x16x32_bf16(ahh[kk], f0, e0, 0, 0, 0);
          e1 = __builtin_amdgcn_mfma_f32_16x16x32_bf16(ahh[kk], f1, e1, 0, 0, 0);
        }
      }
      // ---- gates ----
      float ig = sigm (e0[0] + b4[0]), fg = sigm (e0[1] + b4[1]);
      float gg = ftanh(e0[2] + b4[2]), og = sigm (e0[3] + b4[3]);
      c0 = fg*c0 + ig*gg;
      float hv0 = og * ftanh(c0);
      ig = sigm (e1[0] + b4[0]); fg = sigm (e1[1] + b4[1]);
      gg = ftanh(e1[2] + b4[2]); og = sigm (e1[3] + b4[3]);
      cst1 = fg*cst1 + ig*gg;
      float hv1 = og * ftanh(cst1);
      u16 hh0 = f2bf(hv0), hh1 = f2bf(hv1);
      u32 p0 = (u32)hh0 | (((u32)__shfl((int)hh0, (lane + 16) & 63) & 0xffffu) << 16);
      u32 p1 = (u32)hh1 | (((u32)__shfl((int)hh1, (lane + 16) & 63) & 0xffffu) << 16);
      // TILE-MAJOR protocol store (h2r), then drain + publish
      u32* d32 = (u32*)(h2r + (size_t)(t & 1)*HS) + id*256;
      if (((lane >> 4) & 1) == 0){
        __hip_atomic_store(&d32[b0*8 + (cl >> 1)], p0,
                           __ATOMIC_RELAXED, __HIP_MEMORY_SCOPE_AGENT);
        __hip_atomic_store(&d32[b1*8 + (cl >> 1)], p1,
                           __ATOMIC_RELAXED, __HIP_MEMORY_SCOPE_AGENT);
      }
      asm volatile("s_waitcnt vmcnt(0)" ::: "memory");
      __syncthreads();                     // C
      if (tid == 0) atomicAdd(c2, 1u);
      // deferred, non-protocol h_seq2 stores: TILE-MAJOR, full-line bursts
      if (((lane >> 4) & 1) == 0){
        u32* hs = (u32*)h_seq2 + (size_t)t*(HS/2) + id*256;
        hs[b0*8 + (cl >> 1)] = p0;
        hs[b1*8 + (cl >> 1)] = p1;
      }
    }
  }
}

// ---------------- ragged mean-pool + span head (TILED h_seq2) -------------
// h_seq2 layout: per step t a 32KB tile-major slab [tile][b][16c]. (R9-proven)
__global__ __launch_bounds__(64) void k_pool(const u16* __restrict__ h_seq,
                                             const int* __restrict__ twid,
                                             const float* __restrict__ Wout,
                                             const float* __restrict__ bout,
                                             float* __restrict__ out){
  int bw = blockIdx.x;
  int b = bw >> 8, w = bw & 255;
  const int* tw = twid + b*SS;
  __shared__ int s_lo, s_hi;
  if (threadIdx.x == 0){
    int l = 0, r = SS;
    while (l < r){ int m = (l + r) >> 1; if (tw[m] < w) l = m + 1; else r = m; }
    s_lo = l;
    r = SS;
    while (l < r){ int m = (l + r) >> 1; if (tw[m] < w + 1) l = m + 1; else r = m; }
    s_hi = l;
  }
  __syncthreads();
  int lo = s_lo, hi = s_hi, cnt = hi - lo;
  int lane = threadIdx.x;
  float p0 = 0.f, p1 = 0.f;
  if (cnt > 0){
    const char* hs = (const char*)h_seq;
    const size_t lo_off = (size_t)(lane >> 1)*1024 + (size_t)b*32 + (lane & 1)*16;
    float sum[8] = {0.f,0.f,0.f,0.f,0.f,0.f,0.f,0.f};
    for (int t = lo; t < hi; t++){
      int4 v = *(const int4*)(hs + (size_t)t*32768 + lo_off);
      const u16* u = (const u16*)&v;
      #pragma unroll
      for (int j = 0; j < 8; j++) sum[j] += bf2f(u[j]);
    }
    float inv = 1.f/(float)cnt;
    #pragma unroll
    for (int j = 0; j < 8; j++){
      float pv = sum[j]*inv;
      int d = lane*8 + j;
      p0 += pv * Wout[d];
      p1 += pv * Wout[DD + d];
    }
  }
  #pragma unroll
  for (int off = 32; off; off >>= 1){
    p0 += __shfl_down(p0, off);
    p1 += __shfl_down(p1, off);
  }
  if (lane == 0){
    out[bw*2 + 0] = p0 + bout[0];
    out[bw*2 + 1] = p1 + bout[1];
  }
}

// ---------------- NLL loss over 8192 spans --------------------------------
__global__ __launch_bounds__(256) void k_loss(const float* __restrict__ logits,
                                              const int* __restrict__ labels,
                                              float* __restrict__ out_loss){
  __shared__ float red[256];
  float acc = 0.f;
  for (int i = threadIdx.x; i < BB*MAXW; i += 256){
    float z0 = logits[i*2], z1 = logits[i*2 + 1];
    float m = fmaxf(z0, z1);
    float lse = m + __logf(__expf(z0 - m) + __expf(z1 - m));
    float zl = labels[i] ? z1 : z0;
    acc += (lse - zl);
  }
  red[threadIdx.x] = acc;
  __syncthreads();
  for (int s2 = 128; s2; s2 >>= 1){
    if (threadIdx.x < s2) red[threadIdx.x] += red[threadIdx.x + s2];
    __syncthreads();
  }
  if (threadIdx.x == 0) out_loss[0] = red[0] / (float)(BB*MAXW);
}

extern "C" void kernel_launch(void* const* d_in, const int* in_sizes, int n_in,
                              void* d_out, int out_size, void* d_ws, size_t ws_size,
                              hipStream_t stream){
  (void)in_sizes; (void)n_in; (void)out_size; (void)ws_size;
  const int*   x      = (const int*)  d_in[0];
  const int*   labels = (const int*)  d_in[1];
  const int*   twid   = (const int*)  d_in[2];
  const float* emb    = (const float*)d_in[3];
  const float* Wih    = (const float*)d_in[4];
  const float* Whh    = (const float*)d_in[5];
  const float* bih    = (const float*)d_in[6];
  const float* bhh    = (const float*)d_in[7];
  const float* Wout   = (const float*)d_in[8];
  const float* bout   = (const float*)d_in[9];
  float* out = (float*)d_out;

  char* ws = (char*)d_ws;
  size_t off = 0;
  u16*   h_io   = (u16*)  (ws + off); off += (size_t)BB*SS*DD*2;    // 32 MB
  u16*   h_seq2 = (u16*)  (ws + off); off += (size_t)BB*SS*DD*2;    // 32 MB
  u16*   Wih_b  = (u16*)  (ws + off); off += (size_t)2*G4*DD*2;     // 4 MB
  u16*   Whh_b  = (u16*)  (ws + off); off += (size_t)2*G4*DD*2;     // 4 MB
  float* biasp  = (float*)(ws + off); off += (size_t)2*G4*4;        // 16 KB
  u16*   h1r    = (u16*)  (ws + off); off += (size_t)RING*HS*2;     // 256 KB
  u16*   h2r    = (u16*)  (ws + off); off += (size_t)2*HS*2;        // 64 KB
  u32*   flags  = (u32*)  (ws + off); off += 1024;
  // total ~72.3 MB

  k_prep<<<2048, 256, 0, stream>>>(Wih, Whh, bih, bhh, Wih_b, Whh_b, biasp);
  k_embed<<<BB*SS, 256, 0, stream>>>(x, emb, h_io);

  hipMemsetAsync(flags, 0, 1024, stream);

  k_recur2<<<2*NWG, 256, 0, stream>>>(h_io, Wih_b, Whh_b, biasp,
                                      h1r, h2r, flags, h_seq2);

  k_pool<<<BB*MAXW, 64, 0, stream>>>(h_seq2, twid, Wout, bout, out);
  k_loss<<<1, 256, 0, stream>>>(out, labels, out + BB*MAXW*2);
}